// Round 10
// baseline (118.831 us; speedup 1.0000x reference)
//
#include <hip/hip_runtime.h>

#define NQ 32768
#define NC 8192
#define CFEAT 128
#define CSPLIT 64
#define TILE (NC / CSPLIT)   // 128 coords per split
#define BLK 256
#define QPT 4                // queries per thread (phase 1) — R6-proven
#define QPB (BLK * QPT)      // 1024 queries per block
#define GX (NQ / QPB)        // 32 -> phase-1 grid (32, 64) = 2048 blocks

// ws: [0, 16 MB) u64 bestp[NQ][CSPLIT] — packed (enc(dist)<<32 | idx).
//
// HARNESS LESSONS:
//  R8: no hipLaunchCooperativeKernel / occupancy queries inside
//      kernel_launch (graph capture) — container died. Plain launches only.
//  R9: container died again WITHOUT coop code -> infra flake suspected; this
//      round removes the one untested primitive (64-bit __shfl_xor) to
//      disambiguate. A third crash indicts the u64 design itself.
//
// NUMERICS IS FROZEN (R3/R4 lesson): distance chain per coord is exactly
//   t = mul(-2cx, px); t = fma(-2cy, py, t); t = fma(-2cz, pz, t); d = cc + t
// with cc = ((cx*cx + cy*cy) + cz*cz) pinned by an asm barrier. Flip-free vs
// np's argmin (R0/R2/R5/R6/R7: absmax 0.0). The 3-fma variant flips near-tie
// queries (R3/R4: identical 4.047). pk halves run this exact IEEE-RN
// sequence (R6/R7-proven).
//
// u64 design (R8, kept): each distance computed ONCE. enc is the standard
// order-preserving float->u32 map (neg ? ~bits : bits|0x80000000), so
// u64-min == (min dist, then lowest idx) == np.argmin's global first-index
// (splits partition indices in ascending order). d can be negative (it
// omits ||p||^2) — the encoding handles that. -0.0 cannot arise (cc > 0;
// exact cancellation rounds to +0.0 under RN).
//
// STRUCTURE LESSONS: R6/R7 — phase 1 is latency/occupancy-bound; keep
// 2048 blocks (8/CU). R5 — phase 2 wave-per-query at 8192 blocks (max TLP).
#define BESTP_OFF 0

typedef float f32x2 __attribute__((ext_vector_type(2)));

__device__ __forceinline__ unsigned long long pack_di(float d, int idx) {
  const unsigned int b = __float_as_uint(d);
  const unsigned int msk = (b & 0x80000000u) ? 0xFFFFFFFFu : 0x80000000u;
  return ((unsigned long long)(b ^ msk) << 32) | (unsigned int)idx;
}

// Phase 1: per-split (min dist, first idx) per query, one packed u64 store.
// Pair-interleaved LDS ctab (R6-proven): sA[p]=(x0,x1,y0,y1),
// sB[p]=(z0,z1,w0,w1) -> direct pk operands. Ascending scan with strict <
// keeps the FIRST occurrence of the split-min (np tiebreak within split).
__global__ __launch_bounds__(BLK, 4) void argmin_u64(
    const float* __restrict__ coords, const float* __restrict__ points,
    unsigned long long* __restrict__ bestp) {
  __shared__ float4 sA[TILE / 2];
  __shared__ float4 sB[TILE / 2];

  const int s = blockIdx.y;
  const int base = s * TILE;

  if (threadIdx.x < TILE) {
    const int i = base + threadIdx.x;
    const float cx = coords[i * 3 + 0];
    const float cy = coords[i * 3 + 1];
    const float cz = coords[i * 3 + 2];
    float xx = cx * cx, yy = cy * cy, zz = cz * cz;
    asm volatile("" : "+v"(xx), "+v"(yy), "+v"(zz));  // pin cc order
    const float cc = (xx + yy) + zz;
    const int p = threadIdx.x >> 1, hi = threadIdx.x & 1;
    float* a = (float*)&sA[p];
    float* b = (float*)&sB[p];
    a[0 + hi] = -2.0f * cx;  a[2 + hi] = -2.0f * cy;
    b[0 + hi] = -2.0f * cz;  b[2 + hi] = cc;
  }

  const int q0 = blockIdx.x * QPB + threadIdx.x;
  float px[QPT], py[QPT], pz[QPT], best[QPT];
  int bi[QPT];
  #pragma unroll
  for (int k = 0; k < QPT; ++k) {
    const int q = q0 + k * BLK;
    px[k] = points[q * 3 + 0];
    py[k] = points[q * 3 + 1];
    pz[k] = points[q * 3 + 2];
    best[k] = __builtin_inff();
    bi[k] = 0;
  }
  __syncthreads();

  #pragma unroll 2
  for (int p = 0; p < TILE / 2; ++p) {
    const float4 a = sA[p];          // uniform addr -> broadcast ds_read_b128
    const float4 b = sB[p];
    const f32x2 X = {a.x, a.y}, Y = {a.z, a.w};
    const f32x2 Z = {b.x, b.y}, W = {b.z, b.w};
    const int i0 = base + 2 * p, i1 = i0 + 1;
    #pragma unroll
    for (int k = 0; k < QPT; ++k) {
      f32x2 t = X * (f32x2){px[k], px[k]};                     // pk_mul (RN)
      t = __builtin_elementwise_fma(Y, (f32x2){py[k], py[k]}, t);  // pk_fma
      t = __builtin_elementwise_fma(Z, (f32x2){pz[k], pz[k]}, t);  // pk_fma
      const f32x2 d = W + t;                                   // pk_add (RN)
      bi[k] = (d.x < best[k]) ? i0 : bi[k];    // strict <: first-index wins
      best[k] = fminf(best[k], d.x);
      bi[k] = (d.y < best[k]) ? i1 : bi[k];
      best[k] = fminf(best[k], d.y);
    }
  }

  #pragma unroll
  for (int k = 0; k < QPT; ++k) {
    const int q = q0 + k * BLK;
    bestp[(size_t)q * CSPLIT + s] = pack_di(best[k], bi[k]);
  }
}

// Phase 2: one wave per query (8192 blocks — max TLP, R5 lesson). Lane l
// reads split l's packed u64 (512 B coalesced row), 6-step shfl-min done as
// two 32-bit shuffles per step (semantically identical to a u64 shuffle;
// avoids the untested 64-bit __shfl_xor overload), then gather the
// 128-float feature row with 64 lanes x float2. No rescan.
__global__ __launch_bounds__(256) void gather_u64(
    const unsigned long long* __restrict__ bestp,
    const float* __restrict__ feature, float2* __restrict__ out) {
  const int q = blockIdx.x * 4 + (threadIdx.x >> 6);
  const int l = threadIdx.x & 63;

  unsigned long long m = bestp[(size_t)q * CSPLIT + l];
  #pragma unroll
  for (int off = 32; off; off >>= 1) {
    const unsigned int lo = (unsigned int)m;
    const unsigned int hi = (unsigned int)(m >> 32);
    const unsigned int olo = __shfl_xor(lo, off, 64);
    const unsigned int ohi = __shfl_xor(hi, off, 64);
    const unsigned long long o = ((unsigned long long)ohi << 32) | olo;
    m = (o < m) ? o : m;   // u64 lex min = (min enc(dist), then min idx)
  }
  const int idx = (int)(unsigned int)m;

  const float2* fr = (const float2*)(feature + (size_t)idx * CFEAT);
  out[(size_t)q * (CFEAT / 2) + l] = fr[l];
}

extern "C" void kernel_launch(void* const* d_in, const int* in_sizes, int n_in,
                              void* d_out, int out_size, void* d_ws, size_t ws_size,
                              hipStream_t stream) {
  const float* coords  = (const float*)d_in[0];   // [8192, 3]
  const float* feature = (const float*)d_in[1];   // [8192, 128]
  const float* points  = (const float*)d_in[2];   // [32768, 3]
  float2* out = (float2*)d_out;                   // [32768, 128]

  unsigned long long* bestp =
      (unsigned long long*)((char*)d_ws + BESTP_OFF);

  argmin_u64<<<dim3(GX, CSPLIT), BLK, 0, stream>>>(coords, points, bestp);
  gather_u64<<<NQ / 4, 256, 0, stream>>>(bestp, feature, out);
}

// Round 11
// 100.021 us; speedup vs baseline: 1.1881x; 1.1881x over previous
//
#include <hip/hip_runtime.h>

#define NQ 32768
#define NC 8192
#define CFEAT 128
#define CSPLIT 64
#define TILE (NC / CSPLIT)   // 128 coords per split
#define BLK 256
#define QPT 8                // queries per thread (phase 1): R11's ONE change
#define QPB (BLK * QPT)      // 2048 queries per block
#define GX (NQ / QPB)        // 16 -> phase-1 grid (16, 64) = 1024 blocks

// ws layout: [0, 8 MB) f32 bestd[NQ][CSPLIT] ([q][s]: phase-2 wave reads one
// 256 B row per query — R2-proven); then float4 ctab[NC] (128 KB).
//
// NUMERICS IS FROZEN (R3/R4 lesson): the distance chain MUST be exactly
//   t = mul(cx', px); t = fma(cy', py, t); t = fma(cz', pz, t); d = cc + t
// with ctab entry (-2cx, -2cy, -2cz, ((cx*cx + cy*cy) + cz*cz)).
// Flip-free vs np's argmin (R0/R2/R5/R6/R7/R10: absmax 0.0). The 3-fma
// variant flips near-tie queries (R3/R4: 4.047). pk halves run the exact
// IEEE-RN sequence. Phase 2 consumes the SAME stored ctab bits (R1 lesson).
//
// STRUCTURE LESSONS (counter-backed as of R10):
//  - NO in-loop index tracking: R10 measured it at 53 us vs ~25 (2.5x) —
//    min-only (v_min3) + wave-level equality rescan is the right split.
//  - Phase 1 is LDS-pipe-pressured at QPT=4 (4096 broadcast ds_read_b128
//    per CU); QPT=8 halves that while keeping 16 waves/CU (R7's QPT=16 at
//    8 waves/CU was latency-bound; R5's QPT=8 regression was its phase-2
//    restructure, not QPT).
//  - Phase 2 stays wave-per-query, 8192 blocks (R5 lesson: max TLP).
//  - No cooperative launch / occupancy queries in kernel_launch (R8).
#define BESTD_OFF 0
#define CTAB_OFF ((size_t)NQ * CSPLIT * 4)

typedef float f32x2 __attribute__((ext_vector_type(2)));

// Phase 1: per-split min DISTANCE only — no index tracking.
// Pair-interleaved LDS ctab (R6-proven): sA[p]=(x0,x1,y0,y1),
// sB[p]=(z0,z1,w0,w1) -> direct pk operands. Inner loop per 2 coords per
// query: v_pk_mul + v_pk_fma + v_pk_fma + v_pk_add + v_min3 = 5 insts.
__global__ __launch_bounds__(BLK, 4) void argmin_split(
    const float* __restrict__ coords, const float* __restrict__ points,
    float* __restrict__ bestd, float4* __restrict__ ctab) {
  __shared__ float4 sA[TILE / 2];
  __shared__ float4 sB[TILE / 2];

  const int s = blockIdx.y;
  const int base = s * TILE;

  if (threadIdx.x < TILE) {
    const int i = base + threadIdx.x;
    const float cx = coords[i * 3 + 0];
    const float cy = coords[i * 3 + 1];
    const float cz = coords[i * 3 + 2];
    float xx = cx * cx, yy = cy * cy, zz = cz * cz;
    // Opaque barrier: forbid contracting these products into the adds.
    asm volatile("" : "+v"(xx), "+v"(yy), "+v"(zz));
    const float cc = (xx + yy) + zz;
    const float4 e = make_float4(-2.0f * cx, -2.0f * cy, -2.0f * cz, cc);
    const int p = threadIdx.x >> 1, hi = threadIdx.x & 1;
    float* a = (float*)&sA[p];
    float* b = (float*)&sB[p];
    a[0 + hi] = e.x;  a[2 + hi] = e.y;
    b[0 + hi] = e.z;  b[2 + hi] = e.w;
    if (blockIdx.x == 0) ctab[i] = e;   // persist exact bits for phase 2
  }

  const int q0 = blockIdx.x * QPB + threadIdx.x;
  float px[QPT], py[QPT], pz[QPT], best[QPT];
  #pragma unroll
  for (int k = 0; k < QPT; ++k) {
    const int q = q0 + k * BLK;
    px[k] = points[q * 3 + 0];
    py[k] = points[q * 3 + 1];
    pz[k] = points[q * 3 + 2];
    best[k] = __builtin_inff();
  }
  __syncthreads();

  #pragma unroll 2
  for (int p = 0; p < TILE / 2; ++p) {
    const float4 a = sA[p];          // uniform addr -> broadcast ds_read_b128
    const float4 b = sB[p];
    const f32x2 X = {a.x, a.y}, Y = {a.z, a.w};
    const f32x2 Z = {b.x, b.y}, W = {b.z, b.w};
    #pragma unroll
    for (int k = 0; k < QPT; ++k) {
      f32x2 t = X * (f32x2){px[k], px[k]};                     // pk_mul (RN)
      t = __builtin_elementwise_fma(Y, (f32x2){py[k], py[k]}, t);  // pk_fma
      t = __builtin_elementwise_fma(Z, (f32x2){pz[k], pz[k]}, t);  // pk_fma
      const f32x2 d = W + t;                                   // pk_add (RN)
      best[k] = fminf(fminf(best[k], d.x), d.y);               // v_min3_f32
    }
  }

  #pragma unroll
  for (int k = 0; k < QPT; ++k) {
    const int q = q0 + k * BLK;
    bestd[(size_t)q * CSPLIT + s] = best[k];
  }
}

// Phase 2 (R2-proven, verbatim): one wave per query — reduce 64 split-mins
// (shfl min + ballot/ffs -> lowest winning split); equality-rescan that
// split's 128 coords from the SHARED global ctab (same bits + same frozen
// scalar chain as the pk halves -> hit guaranteed; first match = lowest
// coord). Tiebreak == np.argmin's global first-index. Gather feature row,
// 64 lanes x float2.
__global__ __launch_bounds__(256) void rescan_gather(
    const float4* __restrict__ ctab, const float* __restrict__ points,
    const float* __restrict__ bestd, const float* __restrict__ feature,
    float2* __restrict__ out) {
  const int q = blockIdx.x * 4 + (threadIdx.x >> 6);
  const int l = threadIdx.x & 63;

  // lane l holds split l's min — 256 B coalesced read per wave
  const float v = bestd[(size_t)q * CSPLIT + l];
  float m = v;
  #pragma unroll
  for (int off = 32; off; off >>= 1) m = fminf(m, __shfl_xor(m, off, 64));
  const unsigned long long bs = __ballot(v == m);
  const int sstar = __ffsll(bs) - 1;            // lowest split attaining min

  const float qx = points[q * 3 + 0];           // wave-uniform
  const float qy = points[q * 3 + 1];
  const float qz = points[q * 3 + 2];
  const int b2 = sstar * TILE;

  const float4 c0 = ctab[b2 + l];               // coalesced, lanes consecutive
  const float4 c1 = ctab[b2 + 64 + l];
  float t0 = __fmul_rn(c0.x, qx);                      // FROZEN CHAIN (R2)
  t0 = __fmaf_rn(c0.y, qy, t0);
  t0 = __fmaf_rn(c0.z, qz, t0);
  const float d0 = __fadd_rn(c0.w, t0);
  float t1 = __fmul_rn(c1.x, qx);
  t1 = __fmaf_rn(c1.y, qy, t1);
  t1 = __fmaf_rn(c1.z, qz, t1);
  const float d1 = __fadd_rn(c1.w, t1);

  const unsigned long long b0 = __ballot(d0 == m);
  const unsigned long long b1 = __ballot(d1 == m);
  int off_in;
  if (b0 | b1) {
    off_in = b0 ? (__ffsll(b0) - 1) : (64 + __ffsll(b1) - 1);
  } else {
    // Defense in depth (should be unreachable): true argmin over the 128
    // rescanned candidates, first-index tiebreak.
    float dm = fminf(d0, d1);
    int im = (d0 <= d1) ? l : (64 + l);
    #pragma unroll
    for (int off = 32; off; off >>= 1) {
      const float od = __shfl_xor(dm, off, 64);
      const int oi = __shfl_xor(im, off, 64);
      if (od < dm || (od == dm && oi < im)) { dm = od; im = oi; }
    }
    off_in = im;
  }
  const int idx = b2 + off_in;

  const float2* fr = (const float2*)(feature + (size_t)idx * CFEAT);
  out[(size_t)q * (CFEAT / 2) + l] = fr[l];
}

extern "C" void kernel_launch(void* const* d_in, const int* in_sizes, int n_in,
                              void* d_out, int out_size, void* d_ws, size_t ws_size,
                              hipStream_t stream) {
  const float* coords  = (const float*)d_in[0];   // [8192, 3]
  const float* feature = (const float*)d_in[1];   // [8192, 128]
  const float* points  = (const float*)d_in[2];   // [32768, 3]
  float2* out = (float2*)d_out;                   // [32768, 128]

  float* bestd = (float*)((char*)d_ws + BESTD_OFF);
  float4* ctab = (float4*)((char*)d_ws + CTAB_OFF);

  dim3 grid1(GX, CSPLIT);                         // (16, 64) = 1024 blocks
  argmin_split<<<grid1, BLK, 0, stream>>>(coords, points, bestd, ctab);

  rescan_gather<<<NQ / 4, 256, 0, stream>>>(ctab, points, bestd, feature,
                                            out);
}